// Round 1
// baseline (289.614 us; speedup 1.0000x reference)
//
#include <hip/hip_runtime.h>
#include <hip/hip_bf16.h>

// B=4, S=2048, D=1024 causal attention head, f32 in/out, bf16 MFMA compute.
//
// ws layout (bytes):
//   [0,16MB)    xb    bf16 [8192][1024]
//   [16,22MB)   Wb    bf16 [3072][1024]   (Wq;Wk;Wv stacked, B^T layout)
//   [22,23MB)   biasb f32  [3072]
//   [23,71MB)   QKV   bf16 [8192][3072]   (cols 0:1024=Q, 1024:2048=K, 2048:3072=V)
//   [71,87MB)   Vt    bf16 [4][1024][2048]
//   [87,151MB)  S     f32  [4][2048][2048]; P bf16 overlaid in-place (row pitch 4096 ushorts)
// total 151MB

typedef __attribute__((ext_vector_type(8))) short short8;
typedef __attribute__((ext_vector_type(4))) float f32x4;
typedef __attribute__((ext_vector_type(4))) unsigned short ushort4v;

static __device__ __forceinline__ unsigned short f2b(float f) {
  union { __hip_bfloat16 h; unsigned short u; } cv;
  cv.h = __float2bfloat16(f);
  return cv.u;
}

// ---------------- conversion ----------------
__global__ __launch_bounds__(256) void cvt4(const float* __restrict__ in,
                                            unsigned short* __restrict__ out, int n4) {
  int i = blockIdx.x * blockDim.x + threadIdx.x;
  if (i >= n4) return;
  float4 v = reinterpret_cast<const float4*>(in)[i];
  ushort4v o;
  o.x = f2b(v.x); o.y = f2b(v.y); o.z = f2b(v.z); o.w = f2b(v.w);
  reinterpret_cast<ushort4v*>(out)[i] = o;
}

__global__ __launch_bounds__(256) void concat_bias(const float* __restrict__ a,
                                                   const float* __restrict__ b,
                                                   const float* __restrict__ c,
                                                   float* __restrict__ out) {
  int i = blockIdx.x * blockDim.x + threadIdx.x;  // 3072
  float v = (i < 1024) ? a[i] : (i < 2048) ? b[i - 1024] : c[i - 2048];
  out[i] = v;
}

// ---------------- GEMM: C[M][N] = A[M][K] * B[N][K]^T ----------------
// 128x128 tile, BK=64, 4 waves (2x2), each wave 64x64 (4x4 frags of 16x16x32).
// LDS XOR-swizzle (slot g ^= row&7 per 16B group within 128B row) applied on the
// GLOBAL source address (global_load_lds writes linearly) and on the ds_read.
// MODE 0: bf16 out + bias (projection). MODE 1: f32 out * scale, skip bx>by (scores).
// MODE 2: f32 out, ktiles = (by+1)*2 (PV causal).
template <int MODE>
__global__ __launch_bounds__(256) void gemm128(
    const unsigned short* __restrict__ A, const unsigned short* __restrict__ B,
    void* __restrict__ Cout, const float* __restrict__ bias, float scale,
    int lda, int ldb, int ldc, int ktiles,
    long aStride, long bStride, long cStride) {
  int bx = blockIdx.x, by = blockIdx.y, bz = blockIdx.z;
  if (MODE == 1 && bx > by) return;
  int nkt = (MODE == 2) ? (by + 1) * 2 : ktiles;

  __shared__ unsigned short sA[128 * 64];
  __shared__ unsigned short sB[128 * 64];

  int tid = threadIdx.x;
  int lane = tid & 63;
  int w = tid >> 6;
  int wr = w >> 1, wc = w & 1;

  const unsigned short* Ab = A + bz * aStride + (long)by * 128 * lda;
  const unsigned short* Bb = B + bz * bStride + (long)bx * 128 * ldb;

  f32x4 acc[4][4];
#pragma unroll
  for (int m = 0; m < 4; ++m)
#pragma unroll
    for (int n = 0; n < 4; ++n) acc[m][n] = (f32x4){0.f, 0.f, 0.f, 0.f};

  for (int kt = 0; kt < nkt; ++kt) {
    __syncthreads();  // previous iter's ds_reads done before overwrite
    // stage 32KB: 32 chunks of 1KB, one wave-instruction each; wave w: chunks w*8..w*8+7
#pragma unroll
    for (int c = 0; c < 8; ++c) {
      int chunk = w * 8 + c;
      int half = chunk & 15;
      int L = half * 1024 + lane * 16;  // linear byte offset in sA/sB
      int row = L >> 7;                 // 128B per row (BK=64 bf16)
      int gl = (L >> 4) & 7;
      int gs = gl ^ (row & 7);          // pre-swizzled source group
      if (chunk < 16) {
        const unsigned short* src = Ab + (long)row * lda + kt * 64 + gs * 8;
        __builtin_amdgcn_global_load_lds(
            (const __attribute__((address_space(1))) void*)src,
            (__attribute__((address_space(3))) void*)(sA + half * 512), 16, 0, 0);
      } else {
        const unsigned short* src = Bb + (long)row * ldb + kt * 64 + gs * 8;
        __builtin_amdgcn_global_load_lds(
            (const __attribute__((address_space(1))) void*)src,
            (__attribute__((address_space(3))) void*)(sB + half * 512), 16, 0, 0);
      }
    }
    __syncthreads();  // compiler drains vmcnt(0) before barrier

#pragma unroll
    for (int kk = 0; kk < 2; ++kk) {
      short8 af[4], bfr[4];
#pragma unroll
      for (int m = 0; m < 4; ++m) {
        int row = wr * 64 + m * 16 + (lane & 15);
        int g = kk * 4 + (lane >> 4);
        af[m] = *(const short8*)((const char*)sA + row * 128 + ((g ^ (row & 7)) << 4));
      }
#pragma unroll
      for (int n = 0; n < 4; ++n) {
        int row = wc * 64 + n * 16 + (lane & 15);
        int g = kk * 4 + (lane >> 4);
        bfr[n] = *(const short8*)((const char*)sB + row * 128 + ((g ^ (row & 7)) << 4));
      }
#pragma unroll
      for (int m = 0; m < 4; ++m)
#pragma unroll
        for (int n = 0; n < 4; ++n)
          acc[m][n] = __builtin_amdgcn_mfma_f32_16x16x32_bf16(af[m], bfr[n], acc[m][n], 0, 0, 0);
    }
  }

  // epilogue: C/D layout col=lane&15, row=(lane>>4)*4+reg
  int r0 = by * 128 + wr * 64 + (lane >> 4) * 4;
  int c0 = bx * 128 + wc * 64 + (lane & 15);
  if (MODE == 0) {
    unsigned short* C = (unsigned short*)Cout + bz * cStride;
#pragma unroll
    for (int m = 0; m < 4; ++m)
#pragma unroll
      for (int n = 0; n < 4; ++n) {
        int gc = c0 + n * 16;
        float bv = bias[gc];
#pragma unroll
        for (int r = 0; r < 4; ++r)
          C[(long)(r0 + m * 16 + r) * ldc + gc] = f2b(acc[m][n][r] + bv);
      }
  } else {
    float* C = (float*)Cout + bz * cStride;
#pragma unroll
    for (int m = 0; m < 4; ++m)
#pragma unroll
      for (int n = 0; n < 4; ++n)
#pragma unroll
        for (int r = 0; r < 4; ++r)
          C[(long)(r0 + m * 16 + r) * ldc + c0 + n * 16] = acc[m][n][r] * scale;
  }
}

// ---------------- V transpose: Vt[b][d][s] = V[b][s][d] ----------------
__global__ __launch_bounds__(256) void transpose64(const unsigned short* __restrict__ V,
                                                   unsigned short* __restrict__ Vt) {
  __shared__ unsigned short t[64][72];  // +8 pad breaks bank alignment
  int s0 = blockIdx.x * 64, d0 = blockIdx.y * 64;
  long bz = blockIdx.z;
  const unsigned short* src = V + bz * (2048L * 3072);
  unsigned short* dst = Vt + bz * (1024L * 2048);
  int tid = threadIdx.x;
#pragma unroll
  for (int pp = 0; pp < 2; ++pp) {
    int r = pp * 32 + (tid >> 3);
    int c = (tid & 7) * 8;
    short8 v = *(const short8*)(src + (long)(s0 + r) * 3072 + d0 + c);
    *(short8*)&t[r][c] = v;
  }
  __syncthreads();
#pragma unroll
  for (int pp = 0; pp < 2; ++pp) {
    int d = pp * 32 + (tid >> 3);
    int sc = (tid & 7) * 8;
    short8 v;
#pragma unroll
    for (int k = 0; k < 8; ++k) v[k] = (short)t[sc + k][d];
    *(short8*)(dst + (long)(d0 + d) * 2048 + s0 + sc) = v;
  }
}

// ---------------- causal row softmax, P bf16 written in-place over S ----------------
__global__ __launch_bounds__(256) void softmax_causal(float* __restrict__ S) {
  int row = blockIdx.x;  // 0..8191
  long b = row >> 11;
  int i = row & 2047;
  float* s = S + (b * 2048 + i) * 2048;
  unsigned short* p = (unsigned short*)s;  // in-place, pitch 4096 ushorts
  int n = i + 1;                           // valid causal length
  int jEnd = ((i >> 7) + 1) << 7;          // PV reads exactly this far
  int tid = threadIdx.x;
  __shared__ float red[4];

  float m = -3.0e38f;
  for (int j = tid; j < n; j += 256) m = fmaxf(m, s[j]);
#pragma unroll
  for (int off = 32; off > 0; off >>= 1) m = fmaxf(m, __shfl_xor(m, off));
  if ((tid & 63) == 0) red[tid >> 6] = m;
  __syncthreads();
  m = fmaxf(fmaxf(red[0], red[1]), fmaxf(red[2], red[3]));
  __syncthreads();

  float vals[8];  // 2048/256
  float sum = 0.f;
#pragma unroll
  for (int k = 0; k < 8; ++k) {
    int j = tid + k * 256;
    float e = (j < n) ? __expf(s[j] - m) : 0.f;
    vals[k] = e;
    sum += e;
  }
#pragma unroll
  for (int off = 32; off > 0; off >>= 1) sum += __shfl_xor(sum, off);
  if ((tid & 63) == 0) red[tid >> 6] = sum;
  __syncthreads();  // also guarantees all s[] reads done before in-place writes
  sum = red[0] + red[1] + red[2] + red[3];
  float inv = 1.0f / sum;

#pragma unroll
  for (int k = 0; k < 8; ++k) {
    int j = tid + k * 256;
    if (j < jEnd) p[j] = f2b(vals[k] * inv);
  }
}

extern "C" void kernel_launch(void* const* d_in, const int* in_sizes, int n_in,
                              void* d_out, int out_size, void* d_ws, size_t ws_size,
                              hipStream_t stream) {
  const float* x = (const float*)d_in[0];
  // d_in[1] = additive causal mask — causality handled analytically
  const float* Wq = (const float*)d_in[2];
  const float* bq = (const float*)d_in[3];
  const float* Wk = (const float*)d_in[4];
  const float* bk = (const float*)d_in[5];
  const float* Wv = (const float*)d_in[6];
  const float* bv = (const float*)d_in[7];
  float* out = (float*)d_out;

  char* ws = (char*)d_ws;
  const long MB = 1 << 20;
  unsigned short* xb = (unsigned short*)(ws);            // 16MB
  unsigned short* Wb = (unsigned short*)(ws + 16 * MB);  // 6MB
  float* biasb = (float*)(ws + 22 * MB);                 // 12KB
  unsigned short* QKV = (unsigned short*)(ws + 23 * MB); // 48MB
  unsigned short* Vt = (unsigned short*)(ws + 71 * MB);  // 16MB
  float* Sbuf = (float*)(ws + 87 * MB);                  // 64MB (P overlaid)

  // bf16 conversions
  cvt4<<<8192, 256, 0, stream>>>(x, xb, 2097152);
  cvt4<<<1024, 256, 0, stream>>>(Wq, Wb, 262144);
  cvt4<<<1024, 256, 0, stream>>>(Wk, Wb + 1048576, 262144);
  cvt4<<<1024, 256, 0, stream>>>(Wv, Wb + 2097152, 262144);
  concat_bias<<<12, 256, 0, stream>>>(bq, bk, bv, biasb);

  // fused QKV projection: [8192x1024] x [3072x1024]^T -> bf16 [8192x3072]
  gemm128<0><<<dim3(24, 64, 1), 256, 0, stream>>>(
      xb, Wb, QKV, biasb, 1.0f, 1024, 1024, 3072, 16, 0, 0, 0);

  // Vt[b][d][s]
  transpose64<<<dim3(32, 16, 4), 256, 0, stream>>>(QKV + 2048, Vt);

  // scores = (1/32) Q K^T, lower-triangle blocks only, f32
  gemm128<1><<<dim3(16, 16, 4), 256, 0, stream>>>(
      QKV, QKV + 1024, Sbuf, nullptr, 0.03125f, 3072, 3072, 2048, 16,
      2048L * 3072, 2048L * 3072, 2048L * 2048);

  // causal softmax, P bf16 in-place (row pitch 4096 ushorts)
  softmax_causal<<<8192, 256, 0, stream>>>(Sbuf);

  // out = P V : A = P [2048][2048] (lda 4096), B^T = Vt [1024][2048]
  gemm128<2><<<dim3(8, 16, 4), 256, 0, stream>>>(
      (unsigned short*)Sbuf, Vt, out, nullptr, 1.0f, 4096, 2048, 1024, 0,
      2048L * 4096, 1024L * 2048, 2048L * 1024);
}